// Round 1
// baseline (493.216 us; speedup 1.0000x reference)
//
#include <hip/hip_runtime.h>
#include <hip/hip_bf16.h>
#include <math.h>

typedef __attribute__((ext_vector_type(8))) __bf16 bf16x8;
typedef __attribute__((ext_vector_type(4))) float f32x4;

#define S_LEN 1024
#define D_MODEL 384
#define BATCH 32
#define N3 1152

static __device__ __forceinline__ ushort f2bf(float f) {
    __bf16 h = (__bf16)f;
    return __builtin_bit_cast(ushort, h);
}

// ---------------- kernel 1: positional-encoding table, transposed peT[k][s] ----
__global__ void pe_kernel(float* peT) {
    int idx = blockIdx.x * 256 + threadIdx.x;      // 384*1024 total
    int k = idx >> 10, s = idx & 1023;
    float e = -(float)((k >> 1) * 2) * (logf(10000.0f) / (float)D_MODEL);
    float div = expf(e);
    float a = (float)s * div;
    peT[idx] = (k & 1) ? cosf(a) : sinf(a);
}

// ---------------- kernel 2: W [384][1152] f32 -> Wt [1152][384] bf16 ----------
__global__ void wt_kernel(const float* __restrict__ W, ushort* __restrict__ Wt) {
    __shared__ float tile[32][33];
    int n0 = blockIdx.x * 32, k0 = blockIdx.y * 32;
    int tx = threadIdx.x, ty = threadIdx.y;
#pragma unroll
    for (int r = 0; r < 4; ++r) {
        int kl = ty * 4 + r;
        tile[kl][tx] = W[(size_t)(k0 + kl) * N3 + n0 + tx];
    }
    __syncthreads();
#pragma unroll
    for (int r = 0; r < 4; ++r) {
        int nl = ty * 4 + r;
        Wt[(size_t)(n0 + nl) * D_MODEL + k0 + tx] = f2bf(tile[tx][nl]);
    }
}

// ---------------- kernel 3: A[m][k] = bf16(x[b][k][s] + peT[k][s]) ------------
__global__ void astage_kernel(const float* __restrict__ x, const float* __restrict__ peT,
                              ushort* __restrict__ A) {
    __shared__ float tile[32][33];
    int s0 = blockIdx.x * 32, k0 = blockIdx.y * 32, b = blockIdx.z;
    int tx = threadIdx.x, ty = threadIdx.y;
#pragma unroll
    for (int r = 0; r < 4; ++r) {
        int kl = ty * 4 + r;
        tile[kl][tx] = x[(size_t)(b * D_MODEL + k0 + kl) * S_LEN + s0 + tx]
                     + peT[(size_t)(k0 + kl) * S_LEN + s0 + tx];
    }
    __syncthreads();
#pragma unroll
    for (int r = 0; r < 4; ++r) {
        int sl = ty * 4 + r;
        A[(size_t)(b * S_LEN + s0 + sl) * D_MODEL + k0 + tx] = f2bf(tile[tx][sl]);
    }
}

// ---------------- kernel 4: qkv[m][n] = A[m][:] @ W[:, n] + bias, bf16 out ----
// 128x128 tile, BK=32, 4 waves (2x2), 16x16x32 bf16 MFMA, global_load_lds w=16.
__global__ __launch_bounds__(256) void qkv_gemm(const ushort* __restrict__ A,
                                                const ushort* __restrict__ Wt,
                                                const float* __restrict__ bias,
                                                ushort* __restrict__ qkv) {
    __shared__ __align__(16) ushort As[128 * 32];
    __shared__ __align__(16) ushort Bs[128 * 32];
    int id = blockIdx.x;                  // 2304 = 8 chunks * (9 n * 32 m)
    int g = id / 288, loc = id % 288;
    int nt_ = loc / 32, mt_ = g * 32 + (loc % 32);
    int m0 = mt_ * 128, n0 = nt_ * 128;
    int tid = threadIdx.x;
    int wave = tid >> 6, lane = tid & 63;
    int i16 = lane & 15, gq = lane >> 4;
    int wr = wave >> 1, wc = wave & 1;
    f32x4 acc[4][4] = {};
    for (int ks = 0; ks < 12; ++ks) {
        int k0 = ks * 32;
        __syncthreads();                  // prev compute done before overwrite
#pragma unroll
        for (int i = 0; i < 2; ++i) {
            int off = (wave * 2 + i) * 1024;      // bytes into tile
            int row = (off >> 6) + (lane >> 2);
            int kc = lane & 3;
            const ushort* ga = A + (size_t)(m0 + row) * D_MODEL + k0 + kc * 8;
            __builtin_amdgcn_global_load_lds(
                (const __attribute__((address_space(1))) uint32_t*)ga,
                (__attribute__((address_space(3))) uint32_t*)((char*)As + off), 16, 0, 0);
            const ushort* gb = Wt + (size_t)(n0 + row) * D_MODEL + k0 + kc * 8;
            __builtin_amdgcn_global_load_lds(
                (const __attribute__((address_space(1))) uint32_t*)gb,
                (__attribute__((address_space(3))) uint32_t*)((char*)Bs + off), 16, 0, 0);
        }
        __syncthreads();                  // drains vmcnt: tiles ready
        bf16x8 af[4], bfr[4];
#pragma unroll
        for (int mt = 0; mt < 4; ++mt) {
            int row = wr * 64 + mt * 16 + i16;
            af[mt] = *reinterpret_cast<const bf16x8*>(&As[row * 32 + gq * 8]);
        }
#pragma unroll
        for (int nt = 0; nt < 4; ++nt) {
            int row = wc * 64 + nt * 16 + i16;
            bfr[nt] = *reinterpret_cast<const bf16x8*>(&Bs[row * 32 + gq * 8]);
        }
#pragma unroll
        for (int mt = 0; mt < 4; ++mt)
#pragma unroll
            for (int nt = 0; nt < 4; ++nt)
                acc[mt][nt] = __builtin_amdgcn_mfma_f32_16x16x32_bf16(
                    af[mt], bfr[nt], acc[mt][nt], 0, 0, 0);
    }
#pragma unroll
    for (int nt = 0; nt < 4; ++nt) {
        int n = n0 + wc * 64 + nt * 16 + i16;
        float bv = bias[n];
#pragma unroll
        for (int mt = 0; mt < 4; ++mt)
#pragma unroll
            for (int r = 0; r < 4; ++r) {
                int m = m0 + wr * 64 + mt * 16 + gq * 4 + r;
                qkv[(size_t)m * N3 + n] = f2bf(acc[mt][nt][r] + bv);
            }
    }
}

// ---------------- kernel 5: Vt[b][c][s] = qkv[b*S+s][768+c] ------------------
__global__ void vtrans_kernel(const ushort* __restrict__ qkv, ushort* __restrict__ Vt) {
    __shared__ ushort tile[32][33];
    int s0 = blockIdx.x * 32, c0 = blockIdx.y * 32, b = blockIdx.z;
    int tx = threadIdx.x, ty = threadIdx.y;
#pragma unroll
    for (int r = 0; r < 4; ++r) {
        int sl = ty * 4 + r;
        tile[sl][tx] = qkv[(size_t)(b * S_LEN + s0 + sl) * N3 + 2 * D_MODEL + c0 + tx];
    }
    __syncthreads();
#pragma unroll
    for (int r = 0; r < 4; ++r) {
        int cl = ty * 4 + r;
        Vt[(size_t)(b * D_MODEL + c0 + cl) * S_LEN + s0 + tx] = tile[tx][cl];
    }
}

// ---------------- kernel 6: flash attention, transposed layout ---------------
// Per wave: 16 q columns. St = mfma(K, Q^T) -> lane owns q-col i16, 16 j/lane.
// Softmax reduce = 2 shfl_xor. P^T via per-wave XOR-swizzled LDS. O^T = mfma(Vt, P^T).
__global__ __launch_bounds__(256, 2) void attn_kernel(const ushort* __restrict__ qkv,
                                                      const ushort* __restrict__ Vt,
                                                      float* __restrict__ out) {
    __shared__ __align__(16) ushort Pb[4][1024];   // per-wave 16x64 bf16 P tile
    int id = blockIdx.x;                           // 512 = 8 xcd * (4 b * 16 qt)
    int xcd = id & 7, j = id >> 3;
    int b = xcd * 4 + (j & 3);
    int qt = j >> 2;
    int wave = threadIdx.x >> 6, lane = threadIdx.x & 63;
    int i16 = lane & 15, gq = lane >> 4;
    int q0 = qt * 64 + wave * 16;

    const ushort* Qrow = qkv + (size_t)(b * S_LEN + q0 + i16) * N3;
    bf16x8 qf[12];
#pragma unroll
    for (int kt = 0; kt < 12; ++kt)
        qf[kt] = *reinterpret_cast<const bf16x8*>(Qrow + kt * 32 + gq * 8);

    f32x4 oc[24] = {};
    float m_run = -INFINITY, l_run = 0.0f;
    const float scale = 0.05103103630798287f;      // 1/sqrt(384)
    const float LOG2E = 1.4426950408889634f;
    const ushort* Kbase = qkv + (size_t)b * S_LEN * N3 + D_MODEL;
    const ushort* Vbase = Vt + (size_t)b * D_MODEL * S_LEN;
    ushort* Pw = &Pb[wave][0];

    for (int kv0 = 0; kv0 < S_LEN; kv0 += 64) {
        // ---- St = K . Q^T  (4 j-tiles x 12 k-steps) ----
        f32x4 sacc[4] = {};
#pragma unroll
        for (int kt = 0; kt < 12; ++kt) {
            bf16x8 qv = qf[kt];
#pragma unroll
            for (int jt = 0; jt < 4; ++jt) {
                const ushort* kp = Kbase + (size_t)(kv0 + jt * 16 + i16) * N3 + kt * 32 + gq * 8;
                bf16x8 kf = *reinterpret_cast<const bf16x8*>(kp);
                sacc[jt] = __builtin_amdgcn_mfma_f32_16x16x32_bf16(kf, qv, sacc[jt], 0, 0, 0);
            }
        }
        // ---- online softmax over j (lane-local 16 vals + 2 shuffles) ----
        float sv[16];
        float mt_ = -INFINITY;
#pragma unroll
        for (int jt = 0; jt < 4; ++jt)
#pragma unroll
            for (int r = 0; r < 4; ++r) {
                float v = sacc[jt][r] * scale;
                sv[jt * 4 + r] = v;
                mt_ = fmaxf(mt_, v);
            }
        mt_ = fmaxf(mt_, __shfl_xor(mt_, 16));
        mt_ = fmaxf(mt_, __shfl_xor(mt_, 32));
        float m_new = fmaxf(m_run, mt_);
        float corr = exp2f((m_run - m_new) * LOG2E);
        float lsum = 0.0f;
#pragma unroll
        for (int t = 0; t < 16; ++t) {
            float p = exp2f((sv[t] - m_new) * LOG2E);
            sv[t] = p;
            lsum += p;
        }
        lsum += __shfl_xor(lsum, 16);
        lsum += __shfl_xor(lsum, 32);
        l_run = l_run * corr + lsum;
        m_run = m_new;
#pragma unroll
        for (int ct = 0; ct < 24; ++ct) {
            oc[ct][0] *= corr; oc[ct][1] *= corr; oc[ct][2] *= corr; oc[ct][3] *= corr;
        }
        // ---- P^T -> per-wave LDS (bf16, XOR swizzle on (i&7)<<3 ushorts) ----
#pragma unroll
        for (int jt = 0; jt < 4; ++jt)
#pragma unroll
            for (int rp = 0; rp < 2; ++rp) {
                int jj = jt * 16 + gq * 4 + rp * 2;
                uint u = ((uint)(i16 * 64 + jj)) ^ ((uint)(i16 & 7) << 3);
                uint pk = (uint)f2bf(sv[jt * 4 + rp * 2]) |
                          ((uint)f2bf(sv[jt * 4 + rp * 2 + 1]) << 16);
                *reinterpret_cast<uint*>(&Pw[u]) = pk;
            }
        bf16x8 pf[2];
#pragma unroll
        for (int kt2 = 0; kt2 < 2; ++kt2) {
            uint u = ((uint)(i16 * 64 + kt2 * 32 + gq * 8)) ^ ((uint)(i16 & 7) << 3);
            pf[kt2] = *reinterpret_cast<const bf16x8*>(&Pw[u]);
        }
        // ---- O^T += Vt . P^T  (24 c-tiles x 2 k-steps) ----
#pragma unroll
        for (int ct = 0; ct < 24; ++ct) {
#pragma unroll
            for (int kt2 = 0; kt2 < 2; ++kt2) {
                const ushort* vp = Vbase + (size_t)(ct * 16 + i16) * S_LEN + kv0 + kt2 * 32 + gq * 8;
                bf16x8 vf = *reinterpret_cast<const bf16x8*>(vp);
                oc[ct] = __builtin_amdgcn_mfma_f32_16x16x32_bf16(vf, pf[kt2], oc[ct], 0, 0, 0);
            }
        }
    }
    // ---- normalize + coalesced store: out[b][c][q0+i16] ----
    float inv_l = 1.0f / l_run;
    float* obase = out + (size_t)b * D_MODEL * S_LEN + q0 + i16;
#pragma unroll
    for (int ct = 0; ct < 24; ++ct)
#pragma unroll
        for (int r = 0; r < 4; ++r) {
            int c = ct * 16 + gq * 4 + r;
            obase[(size_t)c * S_LEN] = oc[ct][r] * inv_l;
        }
}

extern "C" void kernel_launch(void* const* d_in, const int* in_sizes, int n_in,
                              void* d_out, int out_size, void* d_ws, size_t ws_size,
                              hipStream_t stream) {
    const float* x    = (const float*)d_in[0];
    const float* W    = (const float*)d_in[1];
    const float* bias = (const float*)d_in[2];
    float* out = (float*)d_out;

    char* ws = (char*)d_ws;
    // ws layout (bytes)
    ushort* A_bf  = (ushort*)(ws);                                  // 25,165,824
    ushort* Wt    = (ushort*)(ws + 25165824);                       //    884,736
    float*  peT   = (float*)(ws + 26050560);                        //  1,572,864
    ushort* qkv   = (ushort*)(ws + 27623424);                       // 75,497,472
    ushort* Vt    = (ushort*)(ws + 103120896);                      // 25,165,824  (total 128,286,720)

    pe_kernel<<<1536, 256, 0, stream>>>(peT);
    wt_kernel<<<dim3(36, 12), dim3(32, 8), 0, stream>>>(W, Wt);
    astage_kernel<<<dim3(32, 12, 32), dim3(32, 8), 0, stream>>>(x, peT, A_bf);
    qkv_gemm<<<2304, 256, 0, stream>>>(A_bf, Wt, bias, qkv);
    vtrans_kernel<<<dim3(32, 12, 32), dim3(32, 8), 0, stream>>>(qkv, Vt);
    attn_kernel<<<512, 256, 0, stream>>>(qkv, Vt, out);
}

// Round 2
// 169.498 us; speedup vs baseline: 2.9099x; 2.9099x over previous
//
#include <hip/hip_runtime.h>
#include <hip/hip_bf16.h>
#include <math.h>

typedef __attribute__((ext_vector_type(8))) __bf16 bf16x8;
typedef __attribute__((ext_vector_type(4))) float f32x4;

#define S_LEN 1024
#define D_MODEL 384
#define BATCH 32
#define N3 1152

static __device__ __forceinline__ ushort f2bf(float f) {
    __bf16 h = (__bf16)f;
    return __builtin_bit_cast(ushort, h);
}

// ---------------- kernel 1: positional-encoding table, transposed peT[k][s] ----
__global__ void pe_kernel(float* peT) {
    int idx = blockIdx.x * 256 + threadIdx.x;      // 384*1024 total
    int k = idx >> 10, s = idx & 1023;
    float e = -(float)((k >> 1) * 2) * (logf(10000.0f) / (float)D_MODEL);
    float div = expf(e);
    float a = (float)s * div;
    peT[idx] = (k & 1) ? cosf(a) : sinf(a);
}

// ---------------- kernel 2: W [384][1152] f32 -> Wt [1152][384] bf16 ----------
__global__ void wt_kernel(const float* __restrict__ W, ushort* __restrict__ Wt) {
    __shared__ float tile[32][33];
    int n0 = blockIdx.x * 32, k0 = blockIdx.y * 32;
    int tx = threadIdx.x, ty = threadIdx.y;
#pragma unroll
    for (int r = 0; r < 4; ++r) {
        int kl = ty * 4 + r;
        tile[kl][tx] = W[(size_t)(k0 + kl) * N3 + n0 + tx];
    }
    __syncthreads();
#pragma unroll
    for (int r = 0; r < 4; ++r) {
        int nl = ty * 4 + r;
        Wt[(size_t)(n0 + nl) * D_MODEL + k0 + tx] = f2bf(tile[tx][nl]);
    }
}

// ---------------- kernel 3: A[m][k] = bf16(x[b][k][s] + peT[k][s]) ------------
__global__ void astage_kernel(const float* __restrict__ x, const float* __restrict__ peT,
                              ushort* __restrict__ A) {
    __shared__ float tile[32][33];
    int s0 = blockIdx.x * 32, k0 = blockIdx.y * 32, b = blockIdx.z;
    int tx = threadIdx.x, ty = threadIdx.y;
#pragma unroll
    for (int r = 0; r < 4; ++r) {
        int kl = ty * 4 + r;
        tile[kl][tx] = x[(size_t)(b * D_MODEL + k0 + kl) * S_LEN + s0 + tx]
                     + peT[(size_t)(k0 + kl) * S_LEN + s0 + tx];
    }
    __syncthreads();
#pragma unroll
    for (int r = 0; r < 4; ++r) {
        int sl = ty * 4 + r;
        A[(size_t)(b * S_LEN + s0 + sl) * D_MODEL + k0 + tx] = f2bf(tile[tx][sl]);
    }
}

// ---------------- kernel 4: qkv[m][n] = A[m][:] @ W[:, n] + bias, bf16 out ----
__global__ __launch_bounds__(256) void qkv_gemm(const ushort* __restrict__ A,
                                                const ushort* __restrict__ Wt,
                                                const float* __restrict__ bias,
                                                ushort* __restrict__ qkv) {
    __shared__ __align__(16) ushort As[128 * 32];
    __shared__ __align__(16) ushort Bs[128 * 32];
    int id = blockIdx.x;                  // 2304 = 8 chunks * (9 n * 32 m)
    int g = id / 288, loc = id % 288;
    int nt_ = loc / 32, mt_ = g * 32 + (loc % 32);
    int m0 = mt_ * 128, n0 = nt_ * 128;
    int tid = threadIdx.x;
    int wave = tid >> 6, lane = tid & 63;
    int i16 = lane & 15, gq = lane >> 4;
    int wr = wave >> 1, wc = wave & 1;
    f32x4 acc[4][4] = {};
    for (int ks = 0; ks < 12; ++ks) {
        int k0 = ks * 32;
        __syncthreads();
#pragma unroll
        for (int i = 0; i < 2; ++i) {
            int off = (wave * 2 + i) * 1024;
            int row = (off >> 6) + (lane >> 2);
            int kc = lane & 3;
            const ushort* ga = A + (size_t)(m0 + row) * D_MODEL + k0 + kc * 8;
            __builtin_amdgcn_global_load_lds(
                (const __attribute__((address_space(1))) uint32_t*)ga,
                (__attribute__((address_space(3))) uint32_t*)((char*)As + off), 16, 0, 0);
            const ushort* gb = Wt + (size_t)(n0 + row) * D_MODEL + k0 + kc * 8;
            __builtin_amdgcn_global_load_lds(
                (const __attribute__((address_space(1))) uint32_t*)gb,
                (__attribute__((address_space(3))) uint32_t*)((char*)Bs + off), 16, 0, 0);
        }
        __syncthreads();
        bf16x8 af[4], bfr[4];
#pragma unroll
        for (int mt = 0; mt < 4; ++mt) {
            int row = wr * 64 + mt * 16 + i16;
            af[mt] = *reinterpret_cast<const bf16x8*>(&As[row * 32 + gq * 8]);
        }
#pragma unroll
        for (int nt = 0; nt < 4; ++nt) {
            int row = wc * 64 + nt * 16 + i16;
            bfr[nt] = *reinterpret_cast<const bf16x8*>(&Bs[row * 32 + gq * 8]);
        }
#pragma unroll
        for (int mt = 0; mt < 4; ++mt)
#pragma unroll
            for (int nt = 0; nt < 4; ++nt)
                acc[mt][nt] = __builtin_amdgcn_mfma_f32_16x16x32_bf16(
                    af[mt], bfr[nt], acc[mt][nt], 0, 0, 0);
    }
#pragma unroll
    for (int nt = 0; nt < 4; ++nt) {
        int n = n0 + wc * 64 + nt * 16 + i16;
        float bv = bias[n];
#pragma unroll
        for (int mt = 0; mt < 4; ++mt)
#pragma unroll
            for (int r = 0; r < 4; ++r) {
                int m = m0 + wr * 64 + mt * 16 + gq * 4 + r;
                qkv[(size_t)m * N3 + n] = f2bf(acc[mt][nt][r] + bv);
            }
    }
}

// ---------------- kernel 5: Vt[b][c][s] = qkv[b*S+s][768+c] ------------------
__global__ void vtrans_kernel(const ushort* __restrict__ qkv, ushort* __restrict__ Vt) {
    __shared__ ushort tile[32][33];
    int s0 = blockIdx.x * 32, c0 = blockIdx.y * 32, b = blockIdx.z;
    int tx = threadIdx.x, ty = threadIdx.y;
#pragma unroll
    for (int r = 0; r < 4; ++r) {
        int sl = ty * 4 + r;
        tile[sl][tx] = qkv[(size_t)(b * S_LEN + s0 + sl) * N3 + 2 * D_MODEL + c0 + tx];
    }
    __syncthreads();
#pragma unroll
    for (int r = 0; r < 4; ++r) {
        int cl = ty * 4 + r;
        Vt[(size_t)(b * D_MODEL + c0 + cl) * S_LEN + s0 + tx] = tile[tx][cl];
    }
}

// ---------------- kernel 6: flash attention, LDS-staged K/Vt -----------------
// 8 waves/block, 128 q per block (16 q per wave), kv-tile 64.
// K[64][384] and Vt[384][64] staged via global_load_lds (linear dest) with
// XOR-swizzle c ^= (row&7)<<4 applied on the per-lane GLOBAL source (m173),
// read back with the same XOR. St = mfma(Ks, Q^T); softmax lane-local;
// P^T through per-wave swizzled LDS; O^T = mfma(Vts, P^T).
__global__ __launch_bounds__(512, 2) void attn_kernel(const ushort* __restrict__ qkv,
                                                      const ushort* __restrict__ Vt,
                                                      float* __restrict__ out) {
    __shared__ __align__(16) ushort Ks[64 * 384];    // 48 KB, rows of 768 B
    __shared__ __align__(16) ushort Vts[384 * 64];   // 48 KB, rows of 128 B
    __shared__ __align__(16) ushort Pb[8][1024];     // 16 KB, per-wave P tile
    int id = blockIdx.x;                             // 256 = 8 xcd * 4 slot * 8 qt
    int xcd = id & 7, slot = (id >> 3) & 3, qt = id >> 5;
    int b = slot * 8 + xcd;                          // all qt of batch b on one XCD
    int tid = threadIdx.x;
    int wave = tid >> 6, lane = tid & 63;
    int i16 = lane & 15, gq = lane >> 4;
    int q0 = qt * 128 + wave * 16;

    const ushort* Qrow = qkv + (size_t)(b * S_LEN + q0 + i16) * N3;
    bf16x8 qf[12];
#pragma unroll
    for (int kt = 0; kt < 12; ++kt)
        qf[kt] = *reinterpret_cast<const bf16x8*>(Qrow + kt * 32 + gq * 8);

    f32x4 oc[24] = {};
    float m_run = -INFINITY, l_run = 0.0f;
    const float scale = 0.05103103630798287f;        // 1/sqrt(384)
    const float LOG2E = 1.4426950408889634f;
    const ushort* Kbase = qkv + (size_t)b * S_LEN * N3 + D_MODEL;
    const ushort* Vbase = Vt + (size_t)b * D_MODEL * S_LEN;
    ushort* Pw = &Pb[wave][0];

    for (int kv0 = 0; kv0 < S_LEN; kv0 += 64) {
        __syncthreads();                             // prev tile fully consumed
        // ---- stage K[64][384]: 6 wave-rounds x 1KB, swizzled source ----
#pragma unroll
        for (int r = 0; r < 6; ++r) {
            int woff = (r * 512 + wave * 64) * 16;   // wave-uniform LDS byte base
            int loff = woff + lane * 16;             // this lane's linear byte
            int row = loff / 768;
            int c = loff - row * 768;
            int sc = c ^ ((row & 7) << 4);
            const ushort* ga = Kbase + (size_t)(kv0 + row) * N3 + (sc >> 1);
            __builtin_amdgcn_global_load_lds(
                (const __attribute__((address_space(1))) uint32_t*)ga,
                (__attribute__((address_space(3))) uint32_t*)((char*)Ks + woff), 16, 0, 0);
        }
        // ---- stage Vt[384][64]: 6 wave-rounds x 1KB, swizzled source ----
#pragma unroll
        for (int r = 0; r < 6; ++r) {
            int woff = (r * 512 + wave * 64) * 16;
            int loff = woff + lane * 16;
            int row = loff >> 7;                     // /128
            int c = loff & 127;
            int sc = c ^ ((row & 7) << 4);
            const ushort* ga = Vbase + (size_t)row * S_LEN + kv0 + (sc >> 1);
            __builtin_amdgcn_global_load_lds(
                (const __attribute__((address_space(1))) uint32_t*)ga,
                (__attribute__((address_space(3))) uint32_t*)((char*)Vts + woff), 16, 0, 0);
        }
        __syncthreads();                             // drains vmcnt: tiles ready

        // ---- St = Ks . Q^T  (4 j-tiles x 12 k-steps) ----
        f32x4 sacc[4] = {};
#pragma unroll
        for (int kt = 0; kt < 12; ++kt) {
            bf16x8 qv = qf[kt];
#pragma unroll
            for (int jt = 0; jt < 4; ++jt) {
                int jrow = jt * 16 + i16;
                int cb = (kt * 64 + gq * 16) ^ ((jrow & 7) << 4);
                bf16x8 kf = *reinterpret_cast<const bf16x8*>((const char*)Ks + jrow * 768 + cb);
                sacc[jt] = __builtin_amdgcn_mfma_f32_16x16x32_bf16(kf, qv, sacc[jt], 0, 0, 0);
            }
        }
        // ---- online softmax over j (lane-local 16 vals + 2 shuffles) ----
        float sv[16];
        float mt_ = -INFINITY;
#pragma unroll
        for (int jt = 0; jt < 4; ++jt)
#pragma unroll
            for (int r = 0; r < 4; ++r) {
                float v = sacc[jt][r] * scale;
                sv[jt * 4 + r] = v;
                mt_ = fmaxf(mt_, v);
            }
        mt_ = fmaxf(mt_, __shfl_xor(mt_, 16));
        mt_ = fmaxf(mt_, __shfl_xor(mt_, 32));
        float m_new = fmaxf(m_run, mt_);
        float corr = exp2f((m_run - m_new) * LOG2E);
        float lsum = 0.0f;
#pragma unroll
        for (int t = 0; t < 16; ++t) {
            float p = exp2f((sv[t] - m_new) * LOG2E);
            sv[t] = p;
            lsum += p;
        }
        lsum += __shfl_xor(lsum, 16);
        lsum += __shfl_xor(lsum, 32);
        l_run = l_run * corr + lsum;
        m_run = m_new;
#pragma unroll
        for (int ct = 0; ct < 24; ++ct) {
            oc[ct][0] *= corr; oc[ct][1] *= corr; oc[ct][2] *= corr; oc[ct][3] *= corr;
        }
        // ---- P^T -> per-wave LDS (bf16, XOR swizzle (i&7)<<3 ushorts) ----
#pragma unroll
        for (int jt = 0; jt < 4; ++jt)
#pragma unroll
            for (int rp = 0; rp < 2; ++rp) {
                int jj = jt * 16 + gq * 4 + rp * 2;
                uint u = ((uint)(i16 * 64 + jj)) ^ ((uint)(i16 & 7) << 3);
                uint pk = (uint)f2bf(sv[jt * 4 + rp * 2]) |
                          ((uint)f2bf(sv[jt * 4 + rp * 2 + 1]) << 16);
                *reinterpret_cast<uint*>(&Pw[u]) = pk;
            }
        bf16x8 pf[2];
#pragma unroll
        for (int kt2 = 0; kt2 < 2; ++kt2) {
            uint u = ((uint)(i16 * 64 + kt2 * 32 + gq * 8)) ^ ((uint)(i16 & 7) << 3);
            pf[kt2] = *reinterpret_cast<const bf16x8*>(&Pw[u]);
        }
        // ---- O^T += Vts . P^T  (24 c-tiles x 2 k-steps) ----
#pragma unroll
        for (int ct = 0; ct < 24; ++ct) {
#pragma unroll
            for (int kt2 = 0; kt2 < 2; ++kt2) {
                int vrow = ct * 16 + i16;
                int cb = (kt2 * 64 + gq * 16) ^ ((vrow & 7) << 4);
                bf16x8 vf = *reinterpret_cast<const bf16x8*>((const char*)Vts + vrow * 128 + cb);
                oc[ct] = __builtin_amdgcn_mfma_f32_16x16x32_bf16(vf, pf[kt2], oc[ct], 0, 0, 0);
            }
        }
    }
    // ---- normalize + coalesced store: out[b][c][q0+i16] ----
    float inv_l = 1.0f / l_run;
    float* obase = out + (size_t)b * D_MODEL * S_LEN + q0 + i16;
#pragma unroll
    for (int ct = 0; ct < 24; ++ct)
#pragma unroll
        for (int r = 0; r < 4; ++r) {
            int c = ct * 16 + gq * 4 + r;
            obase[(size_t)c * S_LEN] = oc[ct][r] * inv_l;
        }
}

extern "C" void kernel_launch(void* const* d_in, const int* in_sizes, int n_in,
                              void* d_out, int out_size, void* d_ws, size_t ws_size,
                              hipStream_t stream) {
    const float* x    = (const float*)d_in[0];
    const float* W    = (const float*)d_in[1];
    const float* bias = (const float*)d_in[2];
    float* out = (float*)d_out;

    char* ws = (char*)d_ws;
    ushort* A_bf  = (ushort*)(ws);                                  // 25,165,824
    ushort* Wt    = (ushort*)(ws + 25165824);                       //    884,736
    float*  peT   = (float*)(ws + 26050560);                        //  1,572,864
    ushort* qkv   = (ushort*)(ws + 27623424);                       // 75,497,472
    ushort* Vt    = (ushort*)(ws + 103120896);                      // 25,165,824

    pe_kernel<<<1536, 256, 0, stream>>>(peT);
    wt_kernel<<<dim3(36, 12), dim3(32, 8), 0, stream>>>(W, Wt);
    astage_kernel<<<dim3(32, 12, 32), dim3(32, 8), 0, stream>>>(x, peT, A_bf);
    qkv_gemm<<<2304, 256, 0, stream>>>(A_bf, Wt, bias, qkv);
    vtrans_kernel<<<dim3(32, 12, 32), dim3(32, 8), 0, stream>>>(qkv, Vt);
    attn_kernel<<<256, 512, 0, stream>>>(qkv, Vt, out);
}

// Round 3
// 162.844 us; speedup vs baseline: 3.0288x; 1.0409x over previous
//
#include <hip/hip_runtime.h>
#include <hip/hip_bf16.h>
#include <math.h>

typedef __attribute__((ext_vector_type(8))) __bf16 bf16x8;
typedef __attribute__((ext_vector_type(4))) float f32x4;

#define S_LEN 1024
#define D_MODEL 384
#define BATCH 32
#define N3 1152
#define KVB 32
#define NT (S_LEN / KVB)

#define MFMA16(a, b, c) __builtin_amdgcn_mfma_f32_16x16x32_bf16((a), (b), (c), 0, 0, 0)

static __device__ __forceinline__ ushort f2bf(float f) {
    __bf16 h = (__bf16)f;
    return __builtin_bit_cast(ushort, h);
}

// ---------------- kernel 1: positional-encoding table, transposed peT[k][s] ----
__global__ void pe_kernel(float* peT) {
    int idx = blockIdx.x * 256 + threadIdx.x;      // 384*1024 total
    int k = idx >> 10, s = idx & 1023;
    float e = -(float)((k >> 1) * 2) * (logf(10000.0f) / (float)D_MODEL);
    float div = expf(e);
    float a = (float)s * div;
    peT[idx] = (k & 1) ? cosf(a) : sinf(a);
}

// ---------------- kernel 2: W [384][1152] f32 -> Wt [1152][384] bf16 ----------
__global__ void wt_kernel(const float* __restrict__ W, ushort* __restrict__ Wt) {
    __shared__ float tile[32][33];
    int n0 = blockIdx.x * 32, k0 = blockIdx.y * 32;
    int tx = threadIdx.x, ty = threadIdx.y;
#pragma unroll
    for (int r = 0; r < 4; ++r) {
        int kl = ty * 4 + r;
        tile[kl][tx] = W[(size_t)(k0 + kl) * N3 + n0 + tx];
    }
    __syncthreads();
#pragma unroll
    for (int r = 0; r < 4; ++r) {
        int nl = ty * 4 + r;
        Wt[(size_t)(n0 + nl) * D_MODEL + k0 + tx] = f2bf(tile[tx][nl]);
    }
}

// ---------------- kernel 3: A[m][k] = bf16(x[b][k][s] + peT[k][s]) ------------
__global__ void astage_kernel(const float* __restrict__ x, const float* __restrict__ peT,
                              ushort* __restrict__ A) {
    __shared__ float tile[32][33];
    int s0 = blockIdx.x * 32, k0 = blockIdx.y * 32, b = blockIdx.z;
    int tx = threadIdx.x, ty = threadIdx.y;
#pragma unroll
    for (int r = 0; r < 4; ++r) {
        int kl = ty * 4 + r;
        tile[kl][tx] = x[(size_t)(b * D_MODEL + k0 + kl) * S_LEN + s0 + tx]
                     + peT[(size_t)(k0 + kl) * S_LEN + s0 + tx];
    }
    __syncthreads();
#pragma unroll
    for (int r = 0; r < 4; ++r) {
        int sl = ty * 4 + r;
        A[(size_t)(b * S_LEN + s0 + sl) * D_MODEL + k0 + tx] = f2bf(tile[tx][sl]);
    }
}

// ---------------- kernel 4: qkv[m][n] = A[m][:] @ W[:, n] + bias, bf16 out ----
__global__ __launch_bounds__(256) void qkv_gemm(const ushort* __restrict__ A,
                                                const ushort* __restrict__ Wt,
                                                const float* __restrict__ bias,
                                                ushort* __restrict__ qkv) {
    __shared__ __align__(16) ushort As[128 * 32];
    __shared__ __align__(16) ushort Bs[128 * 32];
    int id = blockIdx.x;                  // 2304 = 8 chunks * (9 n * 32 m)
    int g = id / 288, loc = id % 288;
    int nt_ = loc / 32, mt_ = g * 32 + (loc % 32);
    int m0 = mt_ * 128, n0 = nt_ * 128;
    int tid = threadIdx.x;
    int wave = tid >> 6, lane = tid & 63;
    int i16 = lane & 15, gq = lane >> 4;
    int wr = wave >> 1, wc = wave & 1;
    f32x4 acc[4][4] = {};
    for (int ks = 0; ks < 12; ++ks) {
        int k0 = ks * 32;
        __syncthreads();
#pragma unroll
        for (int i = 0; i < 2; ++i) {
            int off = (wave * 2 + i) * 1024;
            int row = (off >> 6) + (lane >> 2);
            int kc = lane & 3;
            const ushort* ga = A + (size_t)(m0 + row) * D_MODEL + k0 + kc * 8;
            __builtin_amdgcn_global_load_lds(
                (const __attribute__((address_space(1))) uint32_t*)ga,
                (__attribute__((address_space(3))) uint32_t*)((char*)As + off), 16, 0, 0);
            const ushort* gb = Wt + (size_t)(n0 + row) * D_MODEL + k0 + kc * 8;
            __builtin_amdgcn_global_load_lds(
                (const __attribute__((address_space(1))) uint32_t*)gb,
                (__attribute__((address_space(3))) uint32_t*)((char*)Bs + off), 16, 0, 0);
        }
        __syncthreads();
        bf16x8 af[4], bfr[4];
#pragma unroll
        for (int mt = 0; mt < 4; ++mt) {
            int row = wr * 64 + mt * 16 + i16;
            af[mt] = *reinterpret_cast<const bf16x8*>(&As[row * 32 + gq * 8]);
        }
#pragma unroll
        for (int nt = 0; nt < 4; ++nt) {
            int row = wc * 64 + nt * 16 + i16;
            bfr[nt] = *reinterpret_cast<const bf16x8*>(&Bs[row * 32 + gq * 8]);
        }
#pragma unroll
        for (int mt = 0; mt < 4; ++mt)
#pragma unroll
            for (int nt = 0; nt < 4; ++nt)
                acc[mt][nt] = MFMA16(af[mt], bfr[nt], acc[mt][nt]);
    }
#pragma unroll
    for (int nt = 0; nt < 4; ++nt) {
        int n = n0 + wc * 64 + nt * 16 + i16;
        float bv = bias[n];
#pragma unroll
        for (int mt = 0; mt < 4; ++mt)
#pragma unroll
            for (int r = 0; r < 4; ++r) {
                int m = m0 + wr * 64 + mt * 16 + gq * 4 + r;
                qkv[(size_t)m * N3 + n] = f2bf(acc[mt][nt][r] + bv);
            }
    }
}

// ---------------- kernel 5: Vt[b][c][s] = qkv[b*S+s][768+c] ------------------
__global__ void vtrans_kernel(const ushort* __restrict__ qkv, ushort* __restrict__ Vt) {
    __shared__ ushort tile[32][33];
    int s0 = blockIdx.x * 32, c0 = blockIdx.y * 32, b = blockIdx.z;
    int tx = threadIdx.x, ty = threadIdx.y;
#pragma unroll
    for (int r = 0; r < 4; ++r) {
        int sl = ty * 4 + r;
        tile[sl][tx] = qkv[(size_t)(b * S_LEN + s0 + sl) * N3 + 2 * D_MODEL + c0 + tx];
    }
    __syncthreads();
#pragma unroll
    for (int r = 0; r < 4; ++r) {
        int cl = ty * 4 + r;
        Vt[(size_t)(b * D_MODEL + c0 + cl) * S_LEN + s0 + tx] = tile[tx][cl];
    }
}

// ---------------- kernel 6: flash attention v3 -------------------------------
// 8 waves = 2 (j/c-half: wr) x 4 (q-quarter 32: wc). kv-tile 32, K/V double-
// buffered LDS (24+24 KB each buf), P^T double-buffered (8 KB each).
// Drop-max softmax (fixed max = 0): no online rescale, no cross-wave max.
// Per wave: S^T[16 j][32 q] (12 kt, K-frag feeds 2 MFMA), then
// O^T[192 c][32 q] += V-half . P^T (12 ct, V-frag feeds 2 MFMA).
__global__ __launch_bounds__(512, 2) void attn_kernel(const ushort* __restrict__ qkv,
                                                      const ushort* __restrict__ Vt,
                                                      float* __restrict__ out) {
    __shared__ __align__(16) ushort Ks[2][KVB * 384];     // 2 x 24 KB, rows 768 B
    __shared__ __align__(16) ushort Vts[2][384 * KVB];    // 2 x 24 KB, rows  64 B
    __shared__ __align__(16) ushort Pq[2][128 * KVB];     // 2 x  8 KB, rows  64 B
    int id = blockIdx.x;                                  // 256 = 8 xcd * 4 slot * 8 qt
    int xcd = id & 7, slot = (id >> 3) & 3, qt = id >> 5;
    int b = slot * 8 + xcd;                               // batch grouped per XCD
    int tid = threadIdx.x;
    int wave = tid >> 6, lane = tid & 63;
    int i16 = lane & 15, gq = lane >> 4;
    int wr = wave >> 2, wc = wave & 3;
    int q0 = qt * 128 + wc * 32;

    // ---- Q fragments: B-operand [32k][16q], 12 kt x 2 q-halves (96 VGPR) ----
    bf16x8 qf[12][2];
    const ushort* Qbase = qkv + (size_t)(b * S_LEN + q0) * N3;
#pragma unroll
    for (int kt = 0; kt < 12; ++kt)
#pragma unroll
        for (int qh = 0; qh < 2; ++qh)
            qf[kt][qh] = *reinterpret_cast<const bf16x8*>(
                Qbase + (size_t)(qh * 16 + i16) * N3 + kt * 32 + gq * 8);

    const ushort* Kbase = qkv + (size_t)b * S_LEN * N3 + D_MODEL;
    const ushort* Vbase = Vt + (size_t)b * D_MODEL * S_LEN;

    f32x4 oc[12][2] = {};
    float lsum0 = 0.f, lsum1 = 0.f;
    const float sl2e = 0.05103103630798287f * 1.4426950408889634f;  // scale*log2e

    // stage one kv-tile into buffer bi: K 24 rounds + V 24 rounds, 3+3 per wave
    auto stage = [&](int kv0, int bi) {
#pragma unroll
        for (int i = 0; i < 3; ++i) {
            int woff = (wave * 3 + i) * 1024;
            int loff = woff + lane * 16;
            int row = loff / 768;
            int col = loff - row * 768;
            int sc = col ^ ((row & 7) << 4);              // inverse-swizzled source
            const ushort* ga = Kbase + (size_t)(kv0 + row) * N3 + (sc >> 1);
            __builtin_amdgcn_global_load_lds(
                (const __attribute__((address_space(1))) uint32_t*)ga,
                (__attribute__((address_space(3))) uint32_t*)((char*)&Ks[bi][0] + woff), 16, 0, 0);
        }
#pragma unroll
        for (int i = 0; i < 3; ++i) {
            int woff = (wave * 3 + i) * 1024;
            int loff = woff + lane * 16;
            int row = loff >> 6;
            int col = loff & 63;
            int sc = col ^ ((row & 3) << 4);
            const ushort* ga = Vbase + (size_t)row * S_LEN + kv0 + (sc >> 1);
            __builtin_amdgcn_global_load_lds(
                (const __attribute__((address_space(1))) uint32_t*)ga,
                (__attribute__((address_space(3))) uint32_t*)((char*)&Vts[bi][0] + woff), 16, 0, 0);
        }
    };

    stage(0, 0);
    for (int t = 0; t < NT; ++t) {
        int bi = t & 1;
        __syncthreads();                      // B1: drains vmcnt -> K/V[bi] ready
        if (t + 1 < NT) stage((t + 1) * KVB, bi ^ 1);   // issue-only; lands during QK

        // ---- S^T[j: wr*16..+16][q: wc*32..+32] ----
        f32x4 sacc[2] = {};
        const char* Kb = (const char*)&Ks[bi][0];
        int jrow = wr * 16 + i16;
        int jx = (jrow & 7) << 4;
#pragma unroll
        for (int kt = 0; kt < 12; ++kt) {
            bf16x8 kf = *reinterpret_cast<const bf16x8*>(
                Kb + jrow * 768 + ((kt * 64 + gq * 16) ^ jx));
            sacc[0] = MFMA16(kf, qf[kt][0], sacc[0]);
            sacc[1] = MFMA16(kf, qf[kt][1], sacc[1]);
        }
        // ---- p = exp2(s*scale*log2e)  (no max subtraction), write P^T ----
#pragma unroll
        for (int qh = 0; qh < 2; ++qh) {
            float p0 = exp2f(sacc[qh][0] * sl2e);
            float p1 = exp2f(sacc[qh][1] * sl2e);
            float p2 = exp2f(sacc[qh][2] * sl2e);
            float p3 = exp2f(sacc[qh][3] * sl2e);
            if (qh == 0) lsum0 += (p0 + p1) + (p2 + p3);
            else         lsum1 += (p0 + p1) + (p2 + p3);
            int q = wc * 32 + qh * 16 + i16;
            uint2 val;
            val.x = (uint)f2bf(p0) | ((uint)f2bf(p1) << 16);
            val.y = (uint)f2bf(p2) | ((uint)f2bf(p3) << 16);
            int byte = q * 64 + ((wr * 32 + gq * 8) ^ ((q & 3) << 4));
            *reinterpret_cast<uint2*>((char*)&Pq[bi][0] + byte) = val;
        }
        __syncthreads();                      // B2: P^T ready
        // ---- O^T[c: wr*192..+192][q] += V-half . P^T ----
        bf16x8 pf[2];
#pragma unroll
        for (int qh = 0; qh < 2; ++qh) {
            int q = wc * 32 + qh * 16 + i16;
            pf[qh] = *reinterpret_cast<const bf16x8*>(
                (const char*)&Pq[bi][0] + q * 64 + ((gq * 16) ^ ((q & 3) << 4)));
        }
        const char* Vb = (const char*)&Vts[bi][0];
#pragma unroll
        for (int ct = 0; ct < 12; ++ct) {
            int crow = wr * 192 + ct * 16 + i16;
            bf16x8 vf = *reinterpret_cast<const bf16x8*>(
                Vb + crow * 64 + ((gq * 16) ^ ((crow & 3) << 4)));
            oc[ct][0] = MFMA16(vf, pf[0], oc[ct][0]);
            oc[ct][1] = MFMA16(vf, pf[1], oc[ct][1]);
        }
    }
    // ---- l: reduce over gq (shfl) then over wr (LDS), normalize, store ----
    lsum0 += __shfl_xor(lsum0, 16); lsum0 += __shfl_xor(lsum0, 32);
    lsum1 += __shfl_xor(lsum1, 16); lsum1 += __shfl_xor(lsum1, 32);
    __syncthreads();
    float* Ls = reinterpret_cast<float*>(&Pq[0][0]);    // [2 wr][4 wc][2 qh][16]
    if (gq == 0) {
        Ls[((wr * 4 + wc) * 2 + 0) * 16 + i16] = lsum0;
        Ls[((wr * 4 + wc) * 2 + 1) * 16 + i16] = lsum1;
    }
    __syncthreads();
    float inv0 = 1.0f / (Ls[((0 * 4 + wc) * 2 + 0) * 16 + i16] +
                         Ls[((1 * 4 + wc) * 2 + 0) * 16 + i16]);
    float inv1 = 1.0f / (Ls[((0 * 4 + wc) * 2 + 1) * 16 + i16] +
                         Ls[((1 * 4 + wc) * 2 + 1) * 16 + i16]);
    float* obase = out + (size_t)b * D_MODEL * S_LEN + q0;
#pragma unroll
    for (int ct = 0; ct < 12; ++ct)
#pragma unroll
        for (int r = 0; r < 4; ++r) {
            int c = wr * 192 + ct * 16 + gq * 4 + r;
            obase[(size_t)c * S_LEN + i16] = oc[ct][0][r] * inv0;
            obase[(size_t)c * S_LEN + 16 + i16] = oc[ct][1][r] * inv1;
        }
}

extern "C" void kernel_launch(void* const* d_in, const int* in_sizes, int n_in,
                              void* d_out, int out_size, void* d_ws, size_t ws_size,
                              hipStream_t stream) {
    const float* x    = (const float*)d_in[0];
    const float* W    = (const float*)d_in[1];
    const float* bias = (const float*)d_in[2];
    float* out = (float*)d_out;

    char* ws = (char*)d_ws;
    ushort* A_bf  = (ushort*)(ws);                                  // 25,165,824
    ushort* Wt    = (ushort*)(ws + 25165824);                       //    884,736
    float*  peT   = (float*)(ws + 26050560);                        //  1,572,864
    ushort* qkv   = (ushort*)(ws + 27623424);                       // 75,497,472
    ushort* Vt    = (ushort*)(ws + 103120896);                      // 25,165,824

    pe_kernel<<<1536, 256, 0, stream>>>(peT);
    wt_kernel<<<dim3(36, 12), dim3(32, 8), 0, stream>>>(W, Wt);
    astage_kernel<<<dim3(32, 12, 32), dim3(32, 8), 0, stream>>>(x, peT, A_bf);
    qkv_gemm<<<2304, 256, 0, stream>>>(A_bf, Wt, bias, qkv);
    vtrans_kernel<<<dim3(32, 12, 32), dim3(32, 8), 0, stream>>>(qkv, Vt);
    attn_kernel<<<256, 512, 0, stream>>>(qkv, Vt, out);
}

// Round 4
// 160.602 us; speedup vs baseline: 3.0710x; 1.0140x over previous
//
#include <hip/hip_runtime.h>
#include <hip/hip_bf16.h>
#include <math.h>

typedef __attribute__((ext_vector_type(8))) __bf16 bf16x8;
typedef __attribute__((ext_vector_type(4))) float f32x4;

#define S_LEN 1024
#define D_MODEL 384
#define BATCH 32
#define N3 1152
#define KVB 32
#define NT (S_LEN / KVB)

#define MFMA16(a, b, c) __builtin_amdgcn_mfma_f32_16x16x32_bf16((a), (b), (c), 0, 0, 0)

static __device__ __forceinline__ ushort f2bf(float f) {
    __bf16 h = (__bf16)f;
    return __builtin_bit_cast(ushort, h);
}
static __device__ __forceinline__ uint pk2(float a, float b) {
    return (uint)f2bf(a) | ((uint)f2bf(b) << 16);
}

// ---------------- kernel 1: positional-encoding table, transposed peT[k][s] ----
__global__ void pe_kernel(float* peT) {
    int idx = blockIdx.x * 256 + threadIdx.x;      // 384*1024 total
    int k = idx >> 10, s = idx & 1023;
    float e = -(float)((k >> 1) * 2) * (logf(10000.0f) / (float)D_MODEL);
    float div = expf(e);
    float a = (float)s * div;
    peT[idx] = (k & 1) ? cosf(a) : sinf(a);
}

// ---------------- kernel 2: W [384][1152] f32 -> Wt [1152][384] bf16 ----------
__global__ void wt_kernel(const float* __restrict__ W, ushort* __restrict__ Wt) {
    __shared__ float tile[32][33];
    int n0 = blockIdx.x * 32, k0 = blockIdx.y * 32;
    int tx = threadIdx.x, ty = threadIdx.y;
#pragma unroll
    for (int r = 0; r < 4; ++r) {
        int kl = ty * 4 + r;
        tile[kl][tx] = W[(size_t)(k0 + kl) * N3 + n0 + tx];
    }
    __syncthreads();
#pragma unroll
    for (int r = 0; r < 4; ++r) {
        int nl = ty * 4 + r;
        Wt[(size_t)(n0 + nl) * D_MODEL + k0 + tx] = f2bf(tile[tx][nl]);
    }
}

// ---------------- kernel 3: A[m][k] = bf16(x[b][k][s] + peT[k][s]) ------------
__global__ void astage_kernel(const float* __restrict__ x, const float* __restrict__ peT,
                              ushort* __restrict__ A) {
    __shared__ float tile[32][33];
    int s0 = blockIdx.x * 32, k0 = blockIdx.y * 32, b = blockIdx.z;
    int tx = threadIdx.x, ty = threadIdx.y;
#pragma unroll
    for (int r = 0; r < 4; ++r) {
        int kl = ty * 4 + r;
        tile[kl][tx] = x[(size_t)(b * D_MODEL + k0 + kl) * S_LEN + s0 + tx]
                     + peT[(size_t)(k0 + kl) * S_LEN + s0 + tx];
    }
    __syncthreads();
#pragma unroll
    for (int r = 0; r < 4; ++r) {
        int sl = ty * 4 + r;
        A[(size_t)(b * S_LEN + s0 + sl) * D_MODEL + k0 + tx] = f2bf(tile[tx][sl]);
    }
}

// ---------------- kernel 4: qkv GEMM; V-range blocks write transposed Vt -----
__global__ __launch_bounds__(256) void qkv_gemm(const ushort* __restrict__ A,
                                                const ushort* __restrict__ Wt,
                                                const float* __restrict__ bias,
                                                ushort* __restrict__ qkv,
                                                ushort* __restrict__ Vt) {
    __shared__ __align__(16) ushort As[128 * 32];
    __shared__ __align__(16) ushort Bs[128 * 32];
    int id = blockIdx.x;                  // 2304 = 8 chunks * (9 n * 32 m)
    int g = id / 288, loc = id % 288;
    int nt_ = loc / 32, mt_ = g * 32 + (loc % 32);
    int m0 = mt_ * 128, n0 = nt_ * 128;
    int tid = threadIdx.x;
    int wave = tid >> 6, lane = tid & 63;
    int i16 = lane & 15, gq = lane >> 4;
    int wr = wave >> 1, wc = wave & 1;
    f32x4 acc[4][4] = {};
    for (int ks = 0; ks < 12; ++ks) {
        int k0 = ks * 32;
        __syncthreads();
#pragma unroll
        for (int i = 0; i < 2; ++i) {
            int off = (wave * 2 + i) * 1024;
            int row = (off >> 6) + (lane >> 2);
            int kc = lane & 3;
            const ushort* ga = A + (size_t)(m0 + row) * D_MODEL + k0 + kc * 8;
            __builtin_amdgcn_global_load_lds(
                (const __attribute__((address_space(1))) uint32_t*)ga,
                (__attribute__((address_space(3))) uint32_t*)((char*)As + off), 16, 0, 0);
            const ushort* gb = Wt + (size_t)(n0 + row) * D_MODEL + k0 + kc * 8;
            __builtin_amdgcn_global_load_lds(
                (const __attribute__((address_space(1))) uint32_t*)gb,
                (__attribute__((address_space(3))) uint32_t*)((char*)Bs + off), 16, 0, 0);
        }
        __syncthreads();
        bf16x8 af[4], bfr[4];
#pragma unroll
        for (int mt = 0; mt < 4; ++mt) {
            int row = wr * 64 + mt * 16 + i16;
            af[mt] = *reinterpret_cast<const bf16x8*>(&As[row * 32 + gq * 8]);
        }
#pragma unroll
        for (int nt = 0; nt < 4; ++nt) {
            int row = wc * 64 + nt * 16 + i16;
            bfr[nt] = *reinterpret_cast<const bf16x8*>(&Bs[row * 32 + gq * 8]);
        }
#pragma unroll
        for (int mt = 0; mt < 4; ++mt)
#pragma unroll
            for (int nt = 0; nt < 4; ++nt)
                acc[mt][nt] = MFMA16(af[mt], bfr[nt], acc[mt][nt]);
    }
    if (n0 < 2 * D_MODEL) {
        // Q/K range: write qkv rows (attn reads Q,K from here)
#pragma unroll
        for (int nt = 0; nt < 4; ++nt) {
            int n = n0 + wc * 64 + nt * 16 + i16;
            float bv = bias[n];
#pragma unroll
            for (int mt = 0; mt < 4; ++mt)
#pragma unroll
                for (int r = 0; r < 4; ++r) {
                    int m = m0 + wr * 64 + mt * 16 + gq * 4 + r;
                    qkv[(size_t)m * N3 + n] = f2bf(acc[mt][nt][r] + bv);
                }
        }
    } else {
        // V range: write transposed Vt[b][c][s] directly (vtrans fused)
        int b = m0 >> 10;
        int s_base = (m0 & 1023) + wr * 64;
#pragma unroll
        for (int nt = 0; nt < 4; ++nt) {
            int n = n0 + wc * 64 + nt * 16 + i16;
            float bv = bias[n];
            int c = n - 2 * D_MODEL;
            ushort* vrow = Vt + (size_t)(b * D_MODEL + c) * S_LEN;
#pragma unroll
            for (int mt = 0; mt < 4; ++mt) {
                int s = s_base + mt * 16 + gq * 4;
                ushort4 p4;
                p4.x = f2bf(acc[mt][nt][0] + bv);
                p4.y = f2bf(acc[mt][nt][1] + bv);
                p4.z = f2bf(acc[mt][nt][2] + bv);
                p4.w = f2bf(acc[mt][nt][3] + bv);
                *reinterpret_cast<ushort4*>(vrow + s) = p4;
            }
        }
    }
}

// ---------------- kernel 5: flash attention v4 -------------------------------
// 8 waves, each owns 16 q-columns and the FULL j-range per kv-tile.
// K LDS subtiled [kt][32 j][32 k], V LDS [c][32 j]: all fragment reads are the
// contiguous-1024B pattern (i16*64+gq*16) -> conflict-free, no swizzle.
// P stays in registers: B-frag built via 8 shfl + 4 selects (lane^16/32/48).
// One raw barrier per tile (vmcnt(0)+s_barrier); prefetch never drained.
__global__ __launch_bounds__(512, 2) void attn_kernel(const ushort* __restrict__ qkv,
                                                      const ushort* __restrict__ Vt,
                                                      float* __restrict__ out) {
    __shared__ __align__(16) ushort Ks[2][12 * 32 * 32];   // 2 x 24 KB
    __shared__ __align__(16) ushort Vts[2][384 * 32];      // 2 x 24 KB
    int id = blockIdx.x;                                   // 256 = 8 xcd*4 slot*8 qt
    int xcd = id & 7, slot = (id >> 3) & 3, qt = id >> 5;
    int b = slot * 8 + xcd;                                // batch grouped per XCD
    int tid = threadIdx.x;
    int wave = tid >> 6, lane = tid & 63;
    int i16 = lane & 15, gq = lane >> 4;
    int q0w = qt * 128 + wave * 16;

    const ushort* Kbase = qkv + (size_t)b * S_LEN * N3 + D_MODEL;
    const ushort* Vbase = Vt + (size_t)b * D_MODEL * S_LEN;

    auto stage = [&](int kv0, int bi) {
#pragma unroll
        for (int r = 0; r < 3; ++r) {
            int ii = wave * 3 + r;                   // 0..23
            int kt = ii >> 1, jb = (ii & 1) * 16;
            int j = jb + (lane >> 2), ck = lane & 3;
            const ushort* ga = Kbase + (size_t)(kv0 + j) * N3 + kt * 32 + ck * 8;
            __builtin_amdgcn_global_load_lds(
                (const __attribute__((address_space(1))) uint32_t*)ga,
                (__attribute__((address_space(3))) uint32_t*)((char*)&Ks[bi][0] + ii * 1024), 16, 0, 0);
        }
#pragma unroll
        for (int r = 0; r < 3; ++r) {
            int ii = wave * 3 + r;
            int c = ii * 16 + (lane >> 2), ck = lane & 3;
            const ushort* ga = Vbase + (size_t)c * S_LEN + kv0 + ck * 8;
            __builtin_amdgcn_global_load_lds(
                (const __attribute__((address_space(1))) uint32_t*)ga,
                (__attribute__((address_space(3))) uint32_t*)((char*)&Vts[bi][0] + ii * 1024), 16, 0, 0);
        }
    };

    stage(0, 0);

    // Q fragments: B-operand, lane (gq,i16): Q[q0w+i16][kt*32+gq*8+e]
    bf16x8 qf[12];
    const ushort* Qbase = qkv + (size_t)(b * S_LEN + q0w + i16) * N3;
#pragma unroll
    for (int kt = 0; kt < 12; ++kt)
        qf[kt] = *reinterpret_cast<const bf16x8*>(Qbase + kt * 32 + gq * 8);

    f32x4 oc[24] = {};
    float lsum = 0.f;
    const float sl2e = 0.05103103630798287f * 1.4426950408889634f;
    const int srcA = ((gq & 1) << 5) + i16;     // lane gq=2*(gq&1), same i16
    const int srcB = srcA + 16;                 // lane gq=2*(gq&1)+1
    const int jhsel = gq >> 1;

    for (int t = 0; t < NT; ++t) {
        int bi = t & 1;
        asm volatile("s_waitcnt vmcnt(0)" ::: "memory");   // this tile's K/V landed
        __builtin_amdgcn_s_barrier();
        __builtin_amdgcn_sched_barrier(0);
        if (t + 1 < NT) stage((t + 1) * KVB, bi ^ 1);      // issued, NEVER drained this tile

        // ---- S[32 j][16 q]: sacc0 = j 0..15, sacc1 = j 16..31 ----
        const char* Kb = (const char*)&Ks[bi][0];
        f32x4 sacc0 = {}, sacc1 = {};
        __builtin_amdgcn_s_setprio(1);
#pragma unroll
        for (int kt = 0; kt < 12; ++kt) {
            const char* kp = Kb + kt * 2048 + i16 * 64 + gq * 16;
            bf16x8 kf0 = *reinterpret_cast<const bf16x8*>(kp);
            bf16x8 kf1 = *reinterpret_cast<const bf16x8*>(kp + 1024);
            sacc0 = MFMA16(kf0, qf[kt], sacc0);
            sacc1 = MFMA16(kf1, qf[kt], sacc1);
        }
        __builtin_amdgcn_s_setprio(0);

        // ---- p = exp2(s*scale*log2e) (drop-max), accumulate l ----
        float p00 = exp2f(sacc0[0] * sl2e), p01 = exp2f(sacc0[1] * sl2e);
        float p02 = exp2f(sacc0[2] * sl2e), p03 = exp2f(sacc0[3] * sl2e);
        float p10 = exp2f(sacc1[0] * sl2e), p11 = exp2f(sacc1[1] * sl2e);
        float p12 = exp2f(sacc1[2] * sl2e), p13 = exp2f(sacc1[3] * sl2e);
        lsum += ((p00 + p01) + (p02 + p03)) + ((p10 + p11) + (p12 + p13));

        // ---- in-register P^T -> PV B-frag (8 shfl + 4 selects) ----
        uint u00 = pk2(p00, p01), u01 = pk2(p02, p03);
        uint u10 = pk2(p10, p11), u11 = pk2(p12, p13);
        uint tA0 = __shfl(u00, srcA, 64), tA1 = __shfl(u10, srcA, 64);
        uint tA2 = __shfl(u01, srcA, 64), tA3 = __shfl(u11, srcA, 64);
        uint tB0 = __shfl(u00, srcB, 64), tB1 = __shfl(u10, srcB, 64);
        uint tB2 = __shfl(u01, srcB, 64), tB3 = __shfl(u11, srcB, 64);
        uint4 wv;
        wv.x = jhsel ? tA1 : tA0;   // e0,e1 : P[8gq+0..1][i16]
        wv.y = jhsel ? tA3 : tA2;   // e2,e3
        wv.z = jhsel ? tB1 : tB0;   // e4,e5
        wv.w = jhsel ? tB3 : tB2;   // e6,e7
        bf16x8 pf = __builtin_bit_cast(bf16x8, wv);

        // ---- O[384 c][16 q] += V . P ----
        const char* Vb = (const char*)&Vts[bi][0];
        __builtin_amdgcn_s_setprio(1);
#pragma unroll
        for (int ct = 0; ct < 24; ++ct) {
            bf16x8 vf = *reinterpret_cast<const bf16x8*>(Vb + ct * 1024 + i16 * 64 + gq * 16);
            oc[ct] = MFMA16(vf, pf, oc[ct]);
        }
        __builtin_amdgcn_s_setprio(0);
    }

    // ---- l complete per q after gq-reduction; normalize + store ----
    lsum += __shfl_xor(lsum, 16);
    lsum += __shfl_xor(lsum, 32);
    float inv = 1.0f / lsum;
    float* obase = out + (size_t)b * D_MODEL * S_LEN + q0w + i16;
#pragma unroll
    for (int ct = 0; ct < 24; ++ct)
#pragma unroll
        for (int r = 0; r < 4; ++r) {
            int c = ct * 16 + gq * 4 + r;
            obase[(size_t)c * S_LEN] = oc[ct][r] * inv;
        }
}

extern "C" void kernel_launch(void* const* d_in, const int* in_sizes, int n_in,
                              void* d_out, int out_size, void* d_ws, size_t ws_size,
                              hipStream_t stream) {
    const float* x    = (const float*)d_in[0];
    const float* W    = (const float*)d_in[1];
    const float* bias = (const float*)d_in[2];
    float* out = (float*)d_out;

    char* ws = (char*)d_ws;
    ushort* A_bf  = (ushort*)(ws);                                  // 25,165,824
    ushort* Wt    = (ushort*)(ws + 25165824);                       //    884,736
    float*  peT   = (float*)(ws + 26050560);                        //  1,572,864
    ushort* qkv   = (ushort*)(ws + 27623424);                       // 75,497,472
    ushort* Vt    = (ushort*)(ws + 103120896);                      // 25,165,824

    pe_kernel<<<1536, 256, 0, stream>>>(peT);
    wt_kernel<<<dim3(36, 12), dim3(32, 8), 0, stream>>>(W, Wt);
    astage_kernel<<<dim3(32, 12, 32), dim3(32, 8), 0, stream>>>(x, peT, A_bf);
    qkv_gemm<<<2304, 256, 0, stream>>>(A_bf, Wt, bias, qkv, Vt);
    attn_kernel<<<256, 512, 0, stream>>>(qkv, Vt, out);
}

// Round 5
// 155.736 us; speedup vs baseline: 3.1670x; 1.0312x over previous
//
#include <hip/hip_runtime.h>
#include <hip/hip_bf16.h>
#include <math.h>

typedef __attribute__((ext_vector_type(8))) __bf16 bf16x8;
typedef __attribute__((ext_vector_type(4))) float f32x4;

#define S_LEN 1024
#define D_MODEL 384
#define BATCH 32
#define N3 1152
#define KVB 32
#define NT (S_LEN / KVB)

#define MFMA16(a, b, c) __builtin_amdgcn_mfma_f32_16x16x32_bf16((a), (b), (c), 0, 0, 0)

static __device__ __forceinline__ ushort f2bf(float f) {
    __bf16 h = (__bf16)f;
    return __builtin_bit_cast(ushort, h);
}
static __device__ __forceinline__ uint pk2(float a, float b) {
    return (uint)f2bf(a) | ((uint)f2bf(b) << 16);
}

// ---------------- kernel 1: positional-encoding table, transposed peT[k][s] ----
__global__ void pe_kernel(float* peT) {
    int idx = blockIdx.x * 256 + threadIdx.x;      // 384*1024 total
    int k = idx >> 10, s = idx & 1023;
    float e = -(float)((k >> 1) * 2) * (logf(10000.0f) / (float)D_MODEL);
    float div = expf(e);
    float a = (float)s * div;
    peT[idx] = (k & 1) ? cosf(a) : sinf(a);
}

// ---------------- kernel 2: W [384][1152] f32 -> Wt [1152][384] bf16 ----------
__global__ void wt_kernel(const float* __restrict__ W, ushort* __restrict__ Wt) {
    __shared__ float tile[32][33];
    int n0 = blockIdx.x * 32, k0 = blockIdx.y * 32;
    int tx = threadIdx.x, ty = threadIdx.y;
#pragma unroll
    for (int r = 0; r < 4; ++r) {
        int kl = ty * 4 + r;
        tile[kl][tx] = W[(size_t)(k0 + kl) * N3 + n0 + tx];
    }
    __syncthreads();
#pragma unroll
    for (int r = 0; r < 4; ++r) {
        int nl = ty * 4 + r;
        Wt[(size_t)(n0 + nl) * D_MODEL + k0 + tx] = f2bf(tile[tx][nl]);
    }
}

// ---------------- kernel 3: A[m][k] = bf16(x[b][k][s] + peT[k][s]) ------------
__global__ void astage_kernel(const float* __restrict__ x, const float* __restrict__ peT,
                              ushort* __restrict__ A) {
    __shared__ float tile[32][33];
    int s0 = blockIdx.x * 32, k0 = blockIdx.y * 32, b = blockIdx.z;
    int tx = threadIdx.x, ty = threadIdx.y;
#pragma unroll
    for (int r = 0; r < 4; ++r) {
        int kl = ty * 4 + r;
        tile[kl][tx] = x[(size_t)(b * D_MODEL + k0 + kl) * S_LEN + s0 + tx]
                     + peT[(size_t)(k0 + kl) * S_LEN + s0 + tx];
    }
    __syncthreads();
#pragma unroll
    for (int r = 0; r < 4; ++r) {
        int sl = ty * 4 + r;
        A[(size_t)(b * S_LEN + s0 + sl) * D_MODEL + k0 + tx] = f2bf(tile[tx][sl]);
    }
}

// ---------------- kernel 4: qkv GEMM; V-range blocks write transposed Vt -----
__global__ __launch_bounds__(256) void qkv_gemm(const ushort* __restrict__ A,
                                                const ushort* __restrict__ Wt,
                                                const float* __restrict__ bias,
                                                ushort* __restrict__ qkv,
                                                ushort* __restrict__ Vt) {
    __shared__ __align__(16) ushort As[128 * 32];
    __shared__ __align__(16) ushort Bs[128 * 32];
    int id = blockIdx.x;                  // 2304 = 8 chunks * (9 n * 32 m)
    int g = id / 288, loc = id % 288;
    int nt_ = loc / 32, mt_ = g * 32 + (loc % 32);
    int m0 = mt_ * 128, n0 = nt_ * 128;
    int tid = threadIdx.x;
    int wave = tid >> 6, lane = tid & 63;
    int i16 = lane & 15, gq = lane >> 4;
    int wr = wave >> 1, wc = wave & 1;
    f32x4 acc[4][4] = {};
    for (int ks = 0; ks < 12; ++ks) {
        int k0 = ks * 32;
        __syncthreads();
#pragma unroll
        for (int i = 0; i < 2; ++i) {
            int off = (wave * 2 + i) * 1024;
            int row = (off >> 6) + (lane >> 2);
            int kc = lane & 3;
            const ushort* ga = A + (size_t)(m0 + row) * D_MODEL + k0 + kc * 8;
            __builtin_amdgcn_global_load_lds(
                (const __attribute__((address_space(1))) uint32_t*)ga,
                (__attribute__((address_space(3))) uint32_t*)((char*)As + off), 16, 0, 0);
            const ushort* gb = Wt + (size_t)(n0 + row) * D_MODEL + k0 + kc * 8;
            __builtin_amdgcn_global_load_lds(
                (const __attribute__((address_space(1))) uint32_t*)gb,
                (__attribute__((address_space(3))) uint32_t*)((char*)Bs + off), 16, 0, 0);
        }
        __syncthreads();
        bf16x8 af[4], bfr[4];
#pragma unroll
        for (int mt = 0; mt < 4; ++mt) {
            int row = wr * 64 + mt * 16 + i16;
            af[mt] = *reinterpret_cast<const bf16x8*>(&As[row * 32 + gq * 8]);
        }
#pragma unroll
        for (int nt = 0; nt < 4; ++nt) {
            int row = wc * 64 + nt * 16 + i16;
            bfr[nt] = *reinterpret_cast<const bf16x8*>(&Bs[row * 32 + gq * 8]);
        }
#pragma unroll
        for (int mt = 0; mt < 4; ++mt)
#pragma unroll
            for (int nt = 0; nt < 4; ++nt)
                acc[mt][nt] = MFMA16(af[mt], bfr[nt], acc[mt][nt]);
    }
    if (n0 < 2 * D_MODEL) {
#pragma unroll
        for (int nt = 0; nt < 4; ++nt) {
            int n = n0 + wc * 64 + nt * 16 + i16;
            float bv = bias[n];
#pragma unroll
            for (int mt = 0; mt < 4; ++mt)
#pragma unroll
                for (int r = 0; r < 4; ++r) {
                    int m = m0 + wr * 64 + mt * 16 + gq * 4 + r;
                    qkv[(size_t)m * N3 + n] = f2bf(acc[mt][nt][r] + bv);
                }
        }
    } else {
        // V range: write transposed Vt[b][c][s] directly (vtrans fused)
        int b = m0 >> 10;
        int s_base = (m0 & 1023) + wr * 64;
#pragma unroll
        for (int nt = 0; nt < 4; ++nt) {
            int n = n0 + wc * 64 + nt * 16 + i16;
            float bv = bias[n];
            int c = n - 2 * D_MODEL;
            ushort* vrow = Vt + (size_t)(b * D_MODEL + c) * S_LEN;
#pragma unroll
            for (int mt = 0; mt < 4; ++mt) {
                int s = s_base + mt * 16 + gq * 4;
                ushort4 p4;
                p4.x = f2bf(acc[mt][nt][0] + bv);
                p4.y = f2bf(acc[mt][nt][1] + bv);
                p4.z = f2bf(acc[mt][nt][2] + bv);
                p4.w = f2bf(acc[mt][nt][3] + bv);
                *reinterpret_cast<ushort4*>(vrow + s) = p4;
            }
        }
    }
}

// ---------------- kernel 5: flash attention v5 -------------------------------
// 8 waves = 4 q-groups (32 q, Q in regs) x 2 halves. Wave (qg,h):
//   QK: S[16 j (h-half)][32 q] <- K-half(12KB) x Qreg; 24 MFMA (K-frag->2 MFMA)
//   P exchange: 2KB/qg LDS buffer (bf16), barrier B2 (lgkmcnt only, NO vmcnt)
//   PV: O[192 c (h-half)][32 q] += V-half(12KB) x P; 24 MFMA (V-frag->2 MFMA)
// Per-CU LDS/tile: ~264 KB (vs v4's 768 KB) -> LDS-BW and MFMA pipe balanced.
// B1 = vmcnt(0)+s_barrier: double-buffered K/V prefetch issued after B1, never
// drained mid-tile.
__global__ __launch_bounds__(512, 2) void attn_kernel(const ushort* __restrict__ qkv,
                                                      const ushort* __restrict__ Vt,
                                                      float* __restrict__ out) {
    __shared__ __align__(16) ushort Ks[2][12 * 32 * 32];   // 2 x 24 KB  [kt][32j][32k]
    __shared__ __align__(16) ushort Vts[2][384 * 32];      // 2 x 24 KB  [24ct][16c][32j]
    __shared__ __align__(16) ushort Pq[4][32 * 32];        // 8 KB: [qg][q 32][j 32]
    __shared__ float Ltab[4][2][2][16];                    // [qg][h][qh][i16]
    int id = blockIdx.x;                                   // 256 = 8 xcd*4 slot*8 qt
    int xcd = id & 7, slot = (id >> 3) & 3, qt = id >> 5;
    int b = slot * 8 + xcd;                                // batch grouped per XCD
    int tid = threadIdx.x;
    int wave = tid >> 6, lane = tid & 63;
    int i16 = lane & 15, gq = lane >> 4;
    int qg = wave & 3, h = wave >> 2;                      // h: j-half & c-half role
    int q0w = qt * 128 + qg * 32;

    const ushort* Kbase = qkv + (size_t)b * S_LEN * N3 + D_MODEL;
    const ushort* Vbase = Vt + (size_t)b * D_MODEL * S_LEN;

    auto stage = [&](int kv0, int bi) {
#pragma unroll
        for (int r = 0; r < 3; ++r) {
            int ii = wave * 3 + r;                   // 0..23
            int kt = ii >> 1, jb = (ii & 1) * 16;
            int j = jb + (lane >> 2), ck = lane & 3;
            const ushort* ga = Kbase + (size_t)(kv0 + j) * N3 + kt * 32 + ck * 8;
            __builtin_amdgcn_global_load_lds(
                (const __attribute__((address_space(1))) uint32_t*)ga,
                (__attribute__((address_space(3))) uint32_t*)((char*)&Ks[bi][0] + ii * 1024), 16, 0, 0);
        }
#pragma unroll
        for (int r = 0; r < 3; ++r) {
            int ii = wave * 3 + r;
            int c = ii * 16 + (lane >> 2), ck = lane & 3;
            const ushort* ga = Vbase + (size_t)c * S_LEN + kv0 + ck * 8;
            __builtin_amdgcn_global_load_lds(
                (const __attribute__((address_space(1))) uint32_t*)ga,
                (__attribute__((address_space(3))) uint32_t*)((char*)&Vts[bi][0] + ii * 1024), 16, 0, 0);
        }
    };

    stage(0, 0);

    // Q fragments (B-operand): lane (gq,i16): Q[q0w + qh*16 + i16][kt*32+gq*8..+8]
    bf16x8 qf[12][2];
    const ushort* Qb0 = qkv + (size_t)(b * S_LEN + q0w + i16) * N3;
    const ushort* Qb1 = qkv + (size_t)(b * S_LEN + q0w + 16 + i16) * N3;
#pragma unroll
    for (int kt = 0; kt < 12; ++kt) {
        qf[kt][0] = *reinterpret_cast<const bf16x8*>(Qb0 + kt * 32 + gq * 8);
        qf[kt][1] = *reinterpret_cast<const bf16x8*>(Qb1 + kt * 32 + gq * 8);
    }

    f32x4 oc[12][2] = {};
    float lsum0 = 0.f, lsum1 = 0.f;
    const float sl2e = 0.05103103630798287f * 1.4426950408889634f;

    char* PqB = (char*)&Pq[qg][0];       // this q-group's 2 KB P buffer

    for (int t = 0; t < NT; ++t) {
        int bi = t & 1;
        asm volatile("s_waitcnt vmcnt(0)" ::: "memory");   // tile-t K/V landed
        __builtin_amdgcn_s_barrier();
        __builtin_amdgcn_sched_barrier(0);
        if (t + 1 < NT) stage((t + 1) * KVB, bi ^ 1);      // issued, never drained mid-tile

        // ---- QK: S[h*16..+16 j][32 q], K-frag feeds both q-halves ----
        const char* Kb = (const char*)&Ks[bi][0];
        f32x4 sacc0 = {}, sacc1 = {};
        __builtin_amdgcn_s_setprio(1);
#pragma unroll
        for (int kt = 0; kt < 12; ++kt) {
            bf16x8 kf = *reinterpret_cast<const bf16x8*>(
                Kb + kt * 2048 + (h * 16 + i16) * 64 + gq * 16);
            sacc0 = MFMA16(kf, qf[kt][0], sacc0);
            sacc1 = MFMA16(kf, qf[kt][1], sacc1);
        }
        __builtin_amdgcn_s_setprio(0);

        // ---- p = exp2(s*scale*log2e) (drop-max), accumulate l, write P ----
        // lane (gq,i16) holds S[j = h*16+gq*4+r][q = q0w + qh*16 + i16]
        float p00 = exp2f(sacc0[0] * sl2e), p01 = exp2f(sacc0[1] * sl2e);
        float p02 = exp2f(sacc0[2] * sl2e), p03 = exp2f(sacc0[3] * sl2e);
        float p10 = exp2f(sacc1[0] * sl2e), p11 = exp2f(sacc1[1] * sl2e);
        float p12 = exp2f(sacc1[2] * sl2e), p13 = exp2f(sacc1[3] * sl2e);
        lsum0 += (p00 + p01) + (p02 + p03);
        lsum1 += (p10 + p11) + (p12 + p13);
        // Pq[qg][q][j]: byte = q*64 + j*2 ; j = h*16 + gq*4
        {
            uint2 w0; w0.x = pk2(p00, p01); w0.y = pk2(p02, p03);
            uint2 w1; w1.x = pk2(p10, p11); w1.y = pk2(p12, p13);
            *reinterpret_cast<uint2*>(PqB + i16 * 64 + h * 32 + gq * 8) = w0;
            *reinterpret_cast<uint2*>(PqB + (16 + i16) * 64 + h * 32 + gq * 8) = w1;
        }
        asm volatile("s_waitcnt lgkmcnt(0)" ::: "memory"); // P visible
        __builtin_amdgcn_s_barrier();                      // B2 (no vmcnt drain)
        __builtin_amdgcn_sched_barrier(0);

        // ---- PV: O[h*192..+192 c][32 q] += V-half . P ----
        // P B-frag: lane (gq,i16): P[j=gq*8..+8][q= qh*16+i16]
        bf16x8 pf0 = *reinterpret_cast<const bf16x8*>(PqB + i16 * 64 + gq * 16);
        bf16x8 pf1 = *reinterpret_cast<const bf16x8*>(PqB + (16 + i16) * 64 + gq * 16);
        const char* Vb = (const char*)&Vts[bi][0];
        __builtin_amdgcn_s_setprio(1);
#pragma unroll
        for (int ct = 0; ct < 12; ++ct) {
            bf16x8 vf = *reinterpret_cast<const bf16x8*>(
                Vb + (h * 12 + ct) * 1024 + i16 * 64 + gq * 16);
            oc[ct][0] = MFMA16(vf, pf0, oc[ct][0]);
            oc[ct][1] = MFMA16(vf, pf1, oc[ct][1]);
        }
        __builtin_amdgcn_s_setprio(0);
    }

    // ---- l: reduce over gq (this wave's j-half), then cross-half via LDS ----
    lsum0 += __shfl_xor(lsum0, 16); lsum0 += __shfl_xor(lsum0, 32);
    lsum1 += __shfl_xor(lsum1, 16); lsum1 += __shfl_xor(lsum1, 32);
    __syncthreads();
    if (gq == 0) {
        Ltab[qg][h][0][i16] = lsum0;
        Ltab[qg][h][1][i16] = lsum1;
    }
    __syncthreads();
    float inv0 = 1.0f / (Ltab[qg][0][0][i16] + Ltab[qg][1][0][i16]);
    float inv1 = 1.0f / (Ltab[qg][0][1][i16] + Ltab[qg][1][1][i16]);

    // ---- store O: oc[ct][qh], c = h*192 + ct*16 + gq*4 + r, q = q0w+qh*16+i16
    float* obase = out + (size_t)b * D_MODEL * S_LEN + q0w + i16;
#pragma unroll
    for (int ct = 0; ct < 12; ++ct)
#pragma unroll
        for (int r = 0; r < 4; ++r) {
            int c = h * 192 + ct * 16 + gq * 4 + r;
            obase[(size_t)c * S_LEN] = oc[ct][0][r] * inv0;
            obase[(size_t)c * S_LEN + 16] = oc[ct][1][r] * inv1;
        }
}

extern "C" void kernel_launch(void* const* d_in, const int* in_sizes, int n_in,
                              void* d_out, int out_size, void* d_ws, size_t ws_size,
                              hipStream_t stream) {
    const float* x    = (const float*)d_in[0];
    const float* W    = (const float*)d_in[1];
    const float* bias = (const float*)d_in[2];
    float* out = (float*)d_out;

    char* ws = (char*)d_ws;
    ushort* A_bf  = (ushort*)(ws);                                  // 25,165,824
    ushort* Wt    = (ushort*)(ws + 25165824);                       //    884,736
    float*  peT   = (float*)(ws + 26050560);                        //  1,572,864
    ushort* qkv   = (ushort*)(ws + 27623424);                       // 75,497,472
    ushort* Vt    = (ushort*)(ws + 103120896);                      // 25,165,824

    pe_kernel<<<1536, 256, 0, stream>>>(peT);
    wt_kernel<<<dim3(36, 12), dim3(32, 8), 0, stream>>>(W, Wt);
    astage_kernel<<<dim3(32, 12, 32), dim3(32, 8), 0, stream>>>(x, peT, A_bf);
    qkv_gemm<<<2304, 256, 0, stream>>>(A_bf, Wt, bias, qkv, Vt);
    attn_kernel<<<256, 512, 0, stream>>>(qkv, Vt, out);
}